// Round 6
// baseline (132.629 us; speedup 1.0000x reference)
//
#include <hip/hip_runtime.h>

#define NB 8
#define NS 2048
#define ND 64
#define LOG2E 1.44269504f
// int16 Q8.8 score cache in REGISTERS: step 2^-8 in log2 units, range +-125
#define QSC 256.0f
#define IQS (1.0f / 256.0f)

#define KST 80                  // K tile row stride (halfs): bank-balanced
#define VST 136                 // V tile row stride (halfs): bank-balanced
#define KTILE (128 * KST)       // 10240 halfs per K buffer (128 keys x 64 dims)
#define VTILE (64 * VST)        // 8704 halfs per V buffer (64 dims x 128 keys)

typedef _Float16 half8 __attribute__((ext_vector_type(8)));
typedef _Float16 half4 __attribute__((ext_vector_type(4)));
typedef __attribute__((ext_vector_type(4))) float floatx4;

__device__ __forceinline__ half8 cvt8(const float* p) {
    float4 a = *(const float4*)p;
    float4 b = *(const float4*)(p + 4);
    half8 h = {(_Float16)a.x, (_Float16)a.y, (_Float16)a.z, (_Float16)a.w,
               (_Float16)b.x, (_Float16)b.y, (_Float16)b.z, (_Float16)b.w};
    return h;
}

// ---------------- W prep: fp32 [d][c] -> fp16 Wt[m][c][d] (B-frag friendly) --
__global__ __launch_bounds__(256) void wprep(
    const float* __restrict__ Wq, const float* __restrict__ Wk,
    const float* __restrict__ Wv, _Float16* __restrict__ Wt)
{
    const int m = blockIdx.x;
    const float* W = (m == 0) ? Wq : (m == 1) ? Wk : Wv;
    for (int i = threadIdx.x; i < 64 * 64; i += 256) {
        const int c = i >> 6, d = i & 63;
        Wt[((size_t)m * 64 + c) * 64 + d] = (_Float16)W[d * 64 + c];
    }
}

// ---------------- QKV projection: 64 rows/block, vector fp16 W loads ---------
__global__ __launch_bounds__(256) void qkv_proj(
    const float* __restrict__ x, const _Float16* __restrict__ Wt,
    const float* __restrict__ bq, const float* __restrict__ bk,
    const float* __restrict__ bv,
    _Float16* __restrict__ Qg, _Float16* __restrict__ Kg,
    _Float16* __restrict__ Vt)
{
    __shared__ _Float16 vt[4][64 * 20];   // per-wave V^T staging [col][row]

    const int tid  = threadIdx.x;
    const int wv   = tid >> 6;
    const int l    = tid & 63;
    const int quad = l >> 4;
    const int tx   = l & 15;

    const int b  = blockIdx.x & 7;                  // XCD-pinned batch
    const int n0 = (blockIdx.x >> 3) * 64 + wv * 16;

    const float* xr = x + ((size_t)b * NS + n0 + tx) * ND + quad * 8;
    half8 a0 = cvt8(xr);
    half8 a1 = cvt8(xr + 32);

    const floatx4 zf = {0.f, 0.f, 0.f, 0.f};

#pragma unroll
    for (int ctile = 0; ctile < 12; ++ctile) {
        const int m    = ctile >> 2;
        const int lcol = (ctile & 3) * 16 + tx;

        const _Float16* Wb = Wt + ((size_t)m * 64 + lcol) * 64;
        half8 b0 = *(const half8*)(Wb + quad * 8);
        half8 b1 = *(const half8*)(Wb + 32 + quad * 8);

        floatx4 acc = __builtin_amdgcn_mfma_f32_16x16x32_f16(a0, b0, zf, 0, 0, 0);
        acc = __builtin_amdgcn_mfma_f32_16x16x32_f16(a1, b1, acc, 0, 0, 0);

        const float* Bp = (m == 0) ? bq : (m == 1) ? bk : bv;
        const float bias = Bp[lcol];

        if (m == 0) {
#pragma unroll
            for (int r = 0; r < 4; ++r)
                Qg[((size_t)b * NS + n0 + quad * 4 + r) * ND + lcol] =
                    (_Float16)((acc[r] + bias) * LOG2E);
        } else if (m == 1) {
#pragma unroll
            for (int r = 0; r < 4; ++r)
                Kg[((size_t)b * NS + n0 + quad * 4 + r) * ND + lcol] =
                    (_Float16)(acc[r] + bias);
        } else {
#pragma unroll
            for (int r = 0; r < 4; ++r)
                vt[wv][lcol * 20 + quad * 4 + r] = (_Float16)(acc[r] + bias);
        }
    }
    __syncthreads();
    {
        const int d = l;
        const _Float16* src = &vt[wv][d * 20];
        uint2 p0 = *(const uint2*)(src);
        uint2 p1 = *(const uint2*)(src + 4);
        uint2 p2 = *(const uint2*)(src + 8);
        uint2 p3 = *(const uint2*)(src + 12);
        uint4 q0 = {p0.x, p0.y, p1.x, p1.y};
        uint4 q1 = {p2.x, p2.y, p3.x, p3.y};
        _Float16* dst = Vt + ((size_t)b * ND + d) * NS + n0;
        *(uint4*)(dst)     = q0;
        *(uint4*)(dst + 8) = q1;
    }
}

// ---------------- fused masked attention: register score cache --------------
// Block = 32 q-rows x 512 thr (8 waves = rh(2) x kq(4)), grid 512 = 2 blk/CU.
// Each thread's 128-score share of the 32x2048 score block lives in 32 uint2
// registers as int16 Q8.8 (quantized-consistent L, r1-verified numerics).
// Pass 1 (16 x 128-key K tiles, LDS linear stride-80 rows, bank-balanced):
//   swapped QK mfma(kf,qf) -> lane(quad,tx) reg r = score[key g16+quad*4+r]
//   [row rh*16+tx]; quantize -> sr[t*2+g]; L += exp2(q). QK COMPUTED ONCE.
// Pass 2 (16 x 128-key V tiles): no K, no QK. Unpack sr, e=exp2(q/256),
//   w = e>L/N ? e/L : 0; lane's 4 w ARE the 16x16x16 A-frag -> PV direct
//   from registers. o[dg]: 16 rows x 64 dims x wave's 512 keys.
// Tile stagings 96->32, barriers ~70->38, conflicts: all access patterns
// hand-balanced (staging 4(2s+c), K-read 8(tx&3)+4q, V-read 2-way-even=free).
__global__ __launch_bounds__(512, 4) void attn(
    const _Float16* __restrict__ Qg,
    const _Float16* __restrict__ Kg,
    const _Float16* __restrict__ Vt,
    float* __restrict__ out)
{
    __shared__ __align__(16) _Float16 smem[2 * KTILE];  // K dbuf | V dbuf union, 41KB
    __shared__ float lsh[4 * 32];

    const int tid  = threadIdx.x;
    const int wv   = tid >> 6;
    const int l    = tid & 63;
    const int quad = l >> 4;
    const int tx   = l & 15;
    const int rh   = wv >> 2;       // row-half (16 rows)
    const int kq   = wv & 3;        // key-quarter (512 keys)

    const int b  = blockIdx.x & 7;
    const int q0 = (blockIdx.x >> 3) * 32;

    const _Float16* Qb = Qg + ((size_t)b * NS + q0 + rh * 16) * ND;
    const _Float16* Kb = Kg + (size_t)b * NS * ND;
    const _Float16* Vb = Vt + (size_t)b * ND * NS;

    // Q B-frags: rows rh*16 + tx, k-chunks 0/1
    half8 qf[2];
#pragma unroll
    for (int kc = 0; kc < 2; ++kc)
        qf[kc] = *(const half8*)(Qb + (size_t)tx * ND + kc * 32 + quad * 8);

    const floatx4 zf = {0.f, 0.f, 0.f, 0.f};

    uint2 sr[32];                   // 128 Q8.8 scores, statically indexed

    // ================= pass 1: QK once, L + reg score cache =================
    float lacc = 0.f;
    {
        // staging: thread -> 2x16B of the 20.5KB K tile (128 keys x 80-stride)
        const int skey = tid >> 2;          // 0..127
        const int sc0  = tid & 3;
        const _Float16* Ksrc = Kb + (size_t)skey * ND + sc0 * 8;
        const int kd = skey * KST + sc0 * 8;

        uint4 ga = *(const uint4*)Ksrc;
        uint4 gb = *(const uint4*)(Ksrc + 32);
        *(uint4*)(smem + kd) = ga;
        *(uint4*)(smem + kd + 32) = gb;

#pragma unroll
        for (int t = 0; t < 16; ++t) {
            const int buf = (t & 1) * KTILE;
            __syncthreads();                // tile t staged & visible
            if (t < 15) {
                ga = *(const uint4*)(Ksrc + (size_t)(t + 1) * 128 * ND);
                gb = *(const uint4*)(Ksrc + (size_t)(t + 1) * 128 * ND + 32);
            }
#pragma unroll
            for (int g = 0; g < 2; ++g) {
                const int krow = buf + (kq * 32 + g * 16 + tx) * KST;
                half8 kf0 = *(const half8*)(smem + krow + quad * 8);
                half8 kf1 = *(const half8*)(smem + krow + 32 + quad * 8);
                floatx4 c = __builtin_amdgcn_mfma_f32_16x16x32_f16(kf0, qf[0], zf, 0, 0, 0);
                c = __builtin_amdgcn_mfma_f32_16x16x32_f16(kf1, qf[1], c, 0, 0, 0);
                int ic[4];
#pragma unroll
                for (int r = 0; r < 4; ++r) {
                    float cs = fminf(fmaxf(c[r] * QSC, -32000.f), 32000.f);
                    int v = (int)rintf(cs);
                    ic[r] = v;
                    lacc += __builtin_amdgcn_exp2f((float)v * IQS);  // quantized-consistent
                }
                sr[t * 2 + g].x = (unsigned)(ic[0] & 0xffff) | ((unsigned)ic[1] << 16);
                sr[t * 2 + g].y = (unsigned)(ic[2] & 0xffff) | ((unsigned)ic[3] << 16);
            }
            if (t < 15) {
                *(uint4*)(smem + (buf ^ KTILE) + kd) = ga;
                *(uint4*)(smem + (buf ^ KTILE) + kd + 32) = gb;
            }
        }
    }
    // reduce over quads (lanes tx, tx^16, tx^32, tx^48 share a q-row)
#pragma unroll
    for (int off = 16; off < 64; off <<= 1)
        lacc += __shfl_xor(lacc, off);
    if (quad == 0)
        lsh[kq * 32 + rh * 16 + tx] = lacc;

    // transition: prefetch V tile 0 over the merge barrier
    const int sdim = tid >> 3;              // 0..63
    const int sv0  = tid & 7;
    const _Float16* Vsrc = Vb + (size_t)sdim * NS + sv0 * 8;
    const int vd = sdim * VST + sv0 * 8;

    uint4 gva = *(const uint4*)Vsrc;
    uint4 gvb = *(const uint4*)(Vsrc + 64);
    __syncthreads();                        // lsh ready; pass-1 LDS reads done

    float thr, inv;
    {
        const int row = rh * 16 + tx;
        float L = lsh[row] + lsh[32 + row] + lsh[64 + row] + lsh[96 + row];
        inv = 1.f / L;
        thr = L * (1.f / (float)NS);
    }

    *(uint4*)(smem + vd) = gva;
    *(uint4*)(smem + vd + 64) = gvb;

    floatx4 o[4] = {zf, zf, zf, zf};

    // ================= pass 2: mask + PV from registers =================
#pragma unroll
    for (int t = 0; t < 16; ++t) {
        const int buf = (t & 1) * VTILE;
        __syncthreads();                    // V tile t staged & visible
        if (t < 15) {
            gva = *(const uint4*)(Vsrc + (size_t)(t + 1) * 128);
            gvb = *(const uint4*)(Vsrc + (size_t)(t + 1) * 128 + 64);
        }
#pragma unroll
        for (int g = 0; g < 2; ++g) {
            const uint2 u = sr[t * 2 + g];
            int s0 = (int)(short)(u.x), s1 = (int)(short)(u.x >> 16);
            int s2 = (int)(short)(u.y), s3 = (int)(short)(u.y >> 16);
            float e0 = __builtin_amdgcn_exp2f((float)s0 * IQS);
            float e1 = __builtin_amdgcn_exp2f((float)s1 * IQS);
            float e2 = __builtin_amdgcn_exp2f((float)s2 * IQS);
            float e3 = __builtin_amdgcn_exp2f((float)s3 * IQS);
            float w0 = (e0 > thr) ? e0 * inv : 0.f;
            float w1 = (e1 > thr) ? e1 * inv : 0.f;
            float w2 = (e2 > thr) ? e2 * inv : 0.f;
            float w3 = (e3 > thr) ? e3 * inv : 0.f;
            half4 af = {(_Float16)w0, (_Float16)w1, (_Float16)w2, (_Float16)w3};
#pragma unroll
            for (int dg = 0; dg < 4; ++dg) {
                half4 vf = *(const half4*)(smem + buf + (dg * 16 + tx) * VST +
                                           kq * 32 + g * 16 + quad * 4);
                o[dg] = __builtin_amdgcn_mfma_f32_16x16x16f16(af, vf, o[dg], 0, 0, 0);
            }
        }
        if (t < 15) {
            *(uint4*)(smem + (buf ^ VTILE) + vd) = gva;
            *(uint4*)(smem + (buf ^ VTILE) + vd + 64) = gvb;
        }
    }

    // ================= merge key-quarter partials, store =================
    __syncthreads();                        // all V-tile reads done
    float* osm = (float*)smem;              // [32][68] overlay
    const int orow = rh * 16 + quad * 4;
    if (kq == 0) {
#pragma unroll
        for (int dg = 0; dg < 4; ++dg)
#pragma unroll
            for (int r = 0; r < 4; ++r)
                osm[(orow + r) * 68 + dg * 16 + tx] = o[dg][r];
    }
    __syncthreads();
    if (kq == 1) {
#pragma unroll
        for (int dg = 0; dg < 4; ++dg)
#pragma unroll
            for (int r = 0; r < 4; ++r)
                osm[(orow + r) * 68 + dg * 16 + tx] += o[dg][r];
    }
    __syncthreads();
    if (kq == 2) {
#pragma unroll
        for (int dg = 0; dg < 4; ++dg)
#pragma unroll
            for (int r = 0; r < 4; ++r)
                osm[(orow + r) * 68 + dg * 16 + tx] += o[dg][r];
    }
    __syncthreads();
    if (kq == 3) {
#pragma unroll
        for (int dg = 0; dg < 4; ++dg)
#pragma unroll
            for (int r = 0; r < 4; ++r)
                out[((size_t)b * NS + q0 + orow + r) * ND + dg * 16 + tx] =
                    osm[(orow + r) * 68 + dg * 16 + tx] + o[dg][r];
    }
}

extern "C" void kernel_launch(void* const* d_in, const int* in_sizes, int n_in,
                              void* d_out, int out_size, void* d_ws, size_t ws_size,
                              hipStream_t stream) {
    const float* x  = (const float*)d_in[0];
    const float* Wq = (const float*)d_in[1];
    const float* bq = (const float*)d_in[2];
    const float* Wk = (const float*)d_in[3];
    const float* bk = (const float*)d_in[4];
    const float* Wv = (const float*)d_in[5];
    const float* bv = (const float*)d_in[6];

    // ws: Qg(2MB) Kg(2MB) Vt(2MB) Wt(24KB)
    _Float16* Qg = (_Float16*)d_ws;
    _Float16* Kg = Qg + (size_t)NB * NS * ND;
    _Float16* Vt = Kg + (size_t)NB * NS * ND;
    _Float16* Wt = Vt + (size_t)NB * NS * ND;

    wprep<<<3, 256, 0, stream>>>(Wq, Wk, Wv, Wt);
    qkv_proj<<<NB * (NS / 64), 256, 0, stream>>>(x, Wt, bq, bk, bv, Qg, Kg, Vt);
    attn<<<NB * (NS / 32), 512, 0, stream>>>(Qg, Kg, Vt, (float*)d_out);
}

// Round 7
// 114.764 us; speedup vs baseline: 1.1557x; 1.1557x over previous
//
#include <hip/hip_runtime.h>

#define NB 8
#define NS 2048
#define ND 64
#define LOG2E 1.44269504f
// int16 Q8.8 score cache in REGISTERS: step 2^-8 in log2 units, range +-125
#define QSC 256.0f
#define IQS (1.0f / 256.0f)

#define KST 80                  // K tile row stride (halfs): bank-balanced
#define VST 136                 // V tile row stride (halfs): bank-balanced
#define KTILE (128 * KST)       // 10240 halfs per K buffer (128 keys x 64 dims)
#define VTILE (64 * VST)        // 8704 halfs per V buffer (64 dims x 128 keys)

typedef _Float16 half8 __attribute__((ext_vector_type(8)));
typedef _Float16 half4 __attribute__((ext_vector_type(4)));
typedef __attribute__((ext_vector_type(4))) float floatx4;
typedef unsigned uintx16 __attribute__((ext_vector_type(16)));

__device__ __forceinline__ half8 cvt8(const float* p) {
    float4 a = *(const float4*)p;
    float4 b = *(const float4*)(p + 4);
    half8 h = {(_Float16)a.x, (_Float16)a.y, (_Float16)a.z, (_Float16)a.w,
               (_Float16)b.x, (_Float16)b.y, (_Float16)b.z, (_Float16)b.w};
    return h;
}

// ---------------- W prep: fp32 [d][c] -> fp16 Wt[m][c][d] (B-frag friendly) --
__global__ __launch_bounds__(256) void wprep(
    const float* __restrict__ Wq, const float* __restrict__ Wk,
    const float* __restrict__ Wv, _Float16* __restrict__ Wt)
{
    const int m = blockIdx.x;
    const float* W = (m == 0) ? Wq : (m == 1) ? Wk : Wv;
    for (int i = threadIdx.x; i < 64 * 64; i += 256) {
        const int c = i >> 6, d = i & 63;
        Wt[((size_t)m * 64 + c) * 64 + d] = (_Float16)W[d * 64 + c];
    }
}

// ---------------- QKV projection: 64 rows/block, vector fp16 W loads ---------
__global__ __launch_bounds__(256) void qkv_proj(
    const float* __restrict__ x, const _Float16* __restrict__ Wt,
    const float* __restrict__ bq, const float* __restrict__ bk,
    const float* __restrict__ bv,
    _Float16* __restrict__ Qg, _Float16* __restrict__ Kg,
    _Float16* __restrict__ Vt)
{
    __shared__ _Float16 vt[4][64 * 20];   // per-wave V^T staging [col][row]

    const int tid  = threadIdx.x;
    const int wv   = tid >> 6;
    const int l    = tid & 63;
    const int quad = l >> 4;
    const int tx   = l & 15;

    const int b  = blockIdx.x & 7;                  // XCD-pinned batch
    const int n0 = (blockIdx.x >> 3) * 64 + wv * 16;

    const float* xr = x + ((size_t)b * NS + n0 + tx) * ND + quad * 8;
    half8 a0 = cvt8(xr);
    half8 a1 = cvt8(xr + 32);

    const floatx4 zf = {0.f, 0.f, 0.f, 0.f};

#pragma unroll
    for (int ctile = 0; ctile < 12; ++ctile) {
        const int m    = ctile >> 2;
        const int lcol = (ctile & 3) * 16 + tx;

        const _Float16* Wb = Wt + ((size_t)m * 64 + lcol) * 64;
        half8 b0 = *(const half8*)(Wb + quad * 8);
        half8 b1 = *(const half8*)(Wb + 32 + quad * 8);

        floatx4 acc = __builtin_amdgcn_mfma_f32_16x16x32_f16(a0, b0, zf, 0, 0, 0);
        acc = __builtin_amdgcn_mfma_f32_16x16x32_f16(a1, b1, acc, 0, 0, 0);

        const float* Bp = (m == 0) ? bq : (m == 1) ? bk : bv;
        const float bias = Bp[lcol];

        if (m == 0) {
#pragma unroll
            for (int r = 0; r < 4; ++r)
                Qg[((size_t)b * NS + n0 + quad * 4 + r) * ND + lcol] =
                    (_Float16)((acc[r] + bias) * LOG2E);
        } else if (m == 1) {
#pragma unroll
            for (int r = 0; r < 4; ++r)
                Kg[((size_t)b * NS + n0 + quad * 4 + r) * ND + lcol] =
                    (_Float16)(acc[r] + bias);
        } else {
#pragma unroll
            for (int r = 0; r < 4; ++r)
                vt[wv][lcol * 20 + quad * 4 + r] = (_Float16)(acc[r] + bias);
        }
    }
    __syncthreads();
    {
        const int d = l;
        const _Float16* src = &vt[wv][d * 20];
        uint2 p0 = *(const uint2*)(src);
        uint2 p1 = *(const uint2*)(src + 4);
        uint2 p2 = *(const uint2*)(src + 8);
        uint2 p3 = *(const uint2*)(src + 12);
        uint4 q0 = {p0.x, p0.y, p1.x, p1.y};
        uint4 q1 = {p2.x, p2.y, p3.x, p3.y};
        _Float16* dst = Vt + ((size_t)b * ND + d) * NS + n0;
        *(uint4*)(dst)     = q0;
        *(uint4*)(dst + 8) = q1;
    }
}

// ---------------- fused masked attention: register score cache (16-row) -----
// Block = 16 q-rows x 512 thr (8 waves = 8 key-eighths ke, 256 keys each),
// grid 1024. Per-thread score share = 64 values = int16 Q8.8 packed into TWO
// ext_vector_type(16) uints (sx/sy) -- SSA values, statically indexed via
// full unroll => cannot spill to scratch (r6 lesson: uint2[32] got spilled,
// 150MB scratch traffic). VGPR ~100 < 128 cap (512,4) => no spills, 2 blk/CU.
// Pass 1 (16 x 128-key K tiles, LDS stride-80 rows, bank-balanced): swapped
//   QK mfma(kf,qf) -> lane(quad,tx) reg r = score[key ke*16+quad*4+r][row tx];
//   quantize -> sx[t]/sy[t]; L += exp2(quantized) [consistent softmax]. ONCE.
// Pass 2 (16 x 128-key V tiles): no K, no QK. Unpack, e=exp2(q/256),
//   w = e>L/N ? e/L : 0; lane's 4 w ARE the 16x16x16 A-frag -> PV direct
//   from registers. o[dg]: 16 rows x dims dg*16.. x wave's 256 keys.
// 3-round tree merge over 8 wave-partials (osm overlays smem). ~37 barriers.
__global__ __launch_bounds__(512, 4) void attn(
    const _Float16* __restrict__ Qg,
    const _Float16* __restrict__ Kg,
    const _Float16* __restrict__ Vt,
    float* __restrict__ out)
{
    __shared__ __align__(16) _Float16 smem[2 * KTILE];  // K dbuf | V dbuf | osm union, 41KB
    __shared__ float lsh[8 * 16];

    const int tid  = threadIdx.x;
    const int wv   = tid >> 6;      // = ke, key-eighth
    const int l    = tid & 63;
    const int quad = l >> 4;
    const int tx   = l & 15;

    const int b  = blockIdx.x & 7;
    const int q0 = (blockIdx.x >> 3) * 16;

    const _Float16* Qb = Qg + ((size_t)b * NS + q0) * ND;
    const _Float16* Kb = Kg + (size_t)b * NS * ND;
    const _Float16* Vb = Vt + (size_t)b * ND * NS;

    // Q B-frags: rows tx, k-chunks 0/1 (same for all 8 waves)
    half8 qf[2];
#pragma unroll
    for (int kc = 0; kc < 2; ++kc)
        qf[kc] = *(const half8*)(Qb + (size_t)tx * ND + kc * 32 + quad * 8);

    const floatx4 zf = {0.f, 0.f, 0.f, 0.f};

    uintx16 sx, sy;                 // 64 Q8.8 scores; ext-vector => registers

    // ================= pass 1: QK once, L + reg score cache =================
    float lacc = 0.f;
    {
        // staging: thread -> 2x16B of the 20.5KB K tile (128 keys x 80-stride)
        const int skey = tid >> 2;          // 0..127
        const int sc0  = tid & 3;
        const _Float16* Ksrc = Kb + (size_t)skey * ND + sc0 * 8;
        const int kd = skey * KST + sc0 * 8;

        uint4 ga = *(const uint4*)Ksrc;
        uint4 gb = *(const uint4*)(Ksrc + 32);
        *(uint4*)(smem + kd) = ga;
        *(uint4*)(smem + kd + 32) = gb;

        const int krow = (wv * 16 + tx) * KST;   // wave's K A-frag row base

#pragma unroll
        for (int t = 0; t < 16; ++t) {
            const int buf = (t & 1) * KTILE;
            __syncthreads();                // tile t staged & visible
            if (t < 15) {
                ga = *(const uint4*)(Ksrc + (size_t)(t + 1) * 128 * ND);
                gb = *(const uint4*)(Ksrc + (size_t)(t + 1) * 128 * ND + 32);
            }
            half8 kf0 = *(const half8*)(smem + buf + krow + quad * 8);
            half8 kf1 = *(const half8*)(smem + buf + krow + 32 + quad * 8);
            floatx4 c = __builtin_amdgcn_mfma_f32_16x16x32_f16(kf0, qf[0], zf, 0, 0, 0);
            c = __builtin_amdgcn_mfma_f32_16x16x32_f16(kf1, qf[1], c, 0, 0, 0);
            int ic[4];
#pragma unroll
            for (int r = 0; r < 4; ++r) {
                float cs = fminf(fmaxf(c[r] * QSC, -32000.f), 32000.f);
                int v = (int)rintf(cs);
                ic[r] = v;
                lacc += __builtin_amdgcn_exp2f((float)v * IQS);  // quantized-consistent
            }
            sx[t] = (unsigned)(ic[0] & 0xffff) | ((unsigned)ic[1] << 16);
            sy[t] = (unsigned)(ic[2] & 0xffff) | ((unsigned)ic[3] << 16);
            if (t < 15) {
                *(uint4*)(smem + (buf ^ KTILE) + kd) = ga;
                *(uint4*)(smem + (buf ^ KTILE) + kd + 32) = gb;
            }
        }
    }
    // reduce over quads (lanes tx, tx^16, tx^32, tx^48 share q-row tx)
#pragma unroll
    for (int off = 16; off < 64; off <<= 1)
        lacc += __shfl_xor(lacc, off);
    if (quad == 0)
        lsh[wv * 16 + tx] = lacc;

    // transition: prefetch V tile 0 over the merge barrier
    const int sdim = tid >> 3;              // 0..63
    const int sv0  = tid & 7;
    const _Float16* Vsrc = Vb + (size_t)sdim * NS + sv0 * 8;
    const int vd = sdim * VST + sv0 * 8;

    uint4 gva = *(const uint4*)Vsrc;
    uint4 gvb = *(const uint4*)(Vsrc + 64);
    __syncthreads();                        // lsh ready; pass-1 LDS reads done

    float thr, inv;
    {
        float L = lsh[tx] + lsh[16 + tx] + lsh[32 + tx] + lsh[48 + tx]
                + lsh[64 + tx] + lsh[80 + tx] + lsh[96 + tx] + lsh[112 + tx];
        inv = 1.f / L;
        thr = L * (1.f / (float)NS);
    }

    *(uint4*)(smem + vd) = gva;
    *(uint4*)(smem + vd + 64) = gvb;

    floatx4 o[4] = {zf, zf, zf, zf};

    // ================= pass 2: mask + PV from registers =================
#pragma unroll
    for (int t = 0; t < 16; ++t) {
        const int buf = (t & 1) * VTILE;
        __syncthreads();                    // V tile t staged & visible
        if (t < 15) {
            gva = *(const uint4*)(Vsrc + (size_t)(t + 1) * 128);
            gvb = *(const uint4*)(Vsrc + (size_t)(t + 1) * 128 + 64);
        }
        {
            const unsigned ux = sx[t], uy = sy[t];
            int s0 = (int)(short)(ux), s1 = (int)(short)(ux >> 16);
            int s2 = (int)(short)(uy), s3 = (int)(short)(uy >> 16);
            float e0 = __builtin_amdgcn_exp2f((float)s0 * IQS);
            float e1 = __builtin_amdgcn_exp2f((float)s1 * IQS);
            float e2 = __builtin_amdgcn_exp2f((float)s2 * IQS);
            float e3 = __builtin_amdgcn_exp2f((float)s3 * IQS);
            float w0 = (e0 > thr) ? e0 * inv : 0.f;
            float w1 = (e1 > thr) ? e1 * inv : 0.f;
            float w2 = (e2 > thr) ? e2 * inv : 0.f;
            float w3 = (e3 > thr) ? e3 * inv : 0.f;
            half4 af = {(_Float16)w0, (_Float16)w1, (_Float16)w2, (_Float16)w3};
#pragma unroll
            for (int dg = 0; dg < 4; ++dg) {
                half4 vf = *(const half4*)(smem + buf + (dg * 16 + tx) * VST +
                                           wv * 16 + quad * 4);
                o[dg] = __builtin_amdgcn_mfma_f32_16x16x16f16(af, vf, o[dg], 0, 0, 0);
            }
        }
        if (t < 15) {
            *(uint4*)(smem + (buf ^ VTILE) + vd) = gva;
            *(uint4*)(smem + (buf ^ VTILE) + vd + 64) = gvb;
        }
    }

    // ================= 3-round tree merge over 8 waves, store =================
    __syncthreads();                        // all V-tile reads done; osm overlay safe
    float* osm = (float*)smem;              // 4 slabs of [16][68] f32
    const int orow = quad * 4;
    if (wv >= 4) {
        float* s = osm + (size_t)(wv - 4) * 16 * 68;
#pragma unroll
        for (int dg = 0; dg < 4; ++dg)
#pragma unroll
            for (int r = 0; r < 4; ++r)
                s[(orow + r) * 68 + dg * 16 + tx] = o[dg][r];
    }
    __syncthreads();
    if (wv < 4) {
        const float* s = osm + (size_t)wv * 16 * 68;
#pragma unroll
        for (int dg = 0; dg < 4; ++dg)
#pragma unroll
            for (int r = 0; r < 4; ++r)
                o[dg][r] += s[(orow + r) * 68 + dg * 16 + tx];
    }
    __syncthreads();
    if (wv == 2 || wv == 3) {
        float* s = osm + (size_t)(wv - 2) * 16 * 68;
#pragma unroll
        for (int dg = 0; dg < 4; ++dg)
#pragma unroll
            for (int r = 0; r < 4; ++r)
                s[(orow + r) * 68 + dg * 16 + tx] = o[dg][r];
    }
    __syncthreads();
    if (wv < 2) {
        const float* s = osm + (size_t)wv * 16 * 68;
#pragma unroll
        for (int dg = 0; dg < 4; ++dg)
#pragma unroll
            for (int r = 0; r < 4; ++r)
                o[dg][r] += s[(orow + r) * 68 + dg * 16 + tx];
    }
    __syncthreads();
    if (wv == 1) {
#pragma unroll
        for (int dg = 0; dg < 4; ++dg)
#pragma unroll
            for (int r = 0; r < 4; ++r)
                osm[(orow + r) * 68 + dg * 16 + tx] = o[dg][r];
    }
    __syncthreads();
    if (wv == 0) {
#pragma unroll
        for (int dg = 0; dg < 4; ++dg)
#pragma unroll
            for (int r = 0; r < 4; ++r)
                out[((size_t)b * NS + q0 + orow + r) * ND + dg * 16 + tx] =
                    o[dg][r] + osm[(orow + r) * 68 + dg * 16 + tx];
    }
}

extern "C" void kernel_launch(void* const* d_in, const int* in_sizes, int n_in,
                              void* d_out, int out_size, void* d_ws, size_t ws_size,
                              hipStream_t stream) {
    const float* x  = (const float*)d_in[0];
    const float* Wq = (const float*)d_in[1];
    const float* bq = (const float*)d_in[2];
    const float* Wk = (const float*)d_in[3];
    const float* bk = (const float*)d_in[4];
    const float* Wv = (const float*)d_in[5];
    const float* bv = (const float*)d_in[6];

    // ws: Qg(2MB) Kg(2MB) Vt(2MB) Wt(24KB)
    _Float16* Qg = (_Float16*)d_ws;
    _Float16* Kg = Qg + (size_t)NB * NS * ND;
    _Float16* Vt = Kg + (size_t)NB * NS * ND;
    _Float16* Wt = Vt + (size_t)NB * NS * ND;

    wprep<<<3, 256, 0, stream>>>(Wq, Wk, Wv, Wt);
    qkv_proj<<<NB * (NS / 64), 256, 0, stream>>>(x, Wt, bq, bk, bv, Qg, Kg, Vt);
    attn<<<NB * (NS / 16), 512, 0, stream>>>(Qg, Kg, Vt, (float*)d_out);
}